// Round 3
// baseline (12611.345 us; speedup 1.0000x reference)
//
#include <hip/hip_runtime.h>
#include <stdint.h>

#define B_ 16
#define S_ 2048
#define H_ 512
#define M_ (B_ * S_)  // 32768 rows in all big GEMMs

typedef short short8 __attribute__((ext_vector_type(8)));
typedef float floatx4 __attribute__((ext_vector_type(4)));

// fp32 -> bf16 bits, round-to-nearest-even
static __device__ __forceinline__ unsigned short f2bf(float x) {
  unsigned u = __builtin_bit_cast(unsigned, x);
  unsigned r = (u + 0x7fffu + ((u >> 16) & 1u)) >> 16;
  return (unsigned short)r;
}

// ---------------------------------------------------------------------------
// GEMM: Y[M,N] = X[M,K] @ W[N,K]^T + b1[N] (+ b2[N]), optional tanh epilogue.
// 128x128 tile, BK=16, 256 threads, 8x8 micro-tile. fp32 VALU. (unchanged —
// next round's target for bf16-MFMA conversion.)
// ---------------------------------------------------------------------------
template <int ACT>
__global__ __launch_bounds__(256) void gemm_xwt(
    const float* __restrict__ X, const float* __restrict__ W,
    const float* __restrict__ b1, const float* __restrict__ b2,
    float* __restrict__ Y, int K, int ldy)
{
  __shared__ float As[16][132];
  __shared__ float Bs[16][132];
  const int tid = threadIdx.x;
  const int bm = blockIdx.x, bn = blockIdx.y;
  const int ty = tid >> 4, tx = tid & 15;
  const int lr = tid >> 2, lk = (tid & 3) << 2;
  const float* Xb = X + (size_t)(bm * 128) * K;
  const float* Wb = W + (size_t)(bn * 128) * K;

  float acc[8][8] = {};

  for (int k0 = 0; k0 < K; k0 += 16) {
    float4 xa0 = *(const float4*)(Xb + (size_t)lr * K + k0 + lk);
    float4 xa1 = *(const float4*)(Xb + (size_t)(lr + 64) * K + k0 + lk);
    float4 wa0 = *(const float4*)(Wb + (size_t)lr * K + k0 + lk);
    float4 wa1 = *(const float4*)(Wb + (size_t)(lr + 64) * K + k0 + lk);
    __syncthreads();
    As[lk + 0][lr] = xa0.x; As[lk + 1][lr] = xa0.y; As[lk + 2][lr] = xa0.z; As[lk + 3][lr] = xa0.w;
    As[lk + 0][lr + 64] = xa1.x; As[lk + 1][lr + 64] = xa1.y; As[lk + 2][lr + 64] = xa1.z; As[lk + 3][lr + 64] = xa1.w;
    Bs[lk + 0][lr] = wa0.x; Bs[lk + 1][lr] = wa0.y; Bs[lk + 2][lr] = wa0.z; Bs[lk + 3][lr] = wa0.w;
    Bs[lk + 0][lr + 64] = wa1.x; Bs[lk + 1][lr + 64] = wa1.y; Bs[lk + 2][lr + 64] = wa1.z; Bs[lk + 3][lr + 64] = wa1.w;
    __syncthreads();
#pragma unroll
    for (int kk = 0; kk < 16; ++kk) {
      float4 a0 = *(const float4*)&As[kk][ty * 8];
      float4 a1 = *(const float4*)&As[kk][ty * 8 + 4];
      float4 b0 = *(const float4*)&Bs[kk][tx * 8];
      float4 b1v = *(const float4*)&Bs[kk][tx * 8 + 4];
      float av[8] = {a0.x, a0.y, a0.z, a0.w, a1.x, a1.y, a1.z, a1.w};
      float bv[8] = {b0.x, b0.y, b0.z, b0.w, b1v.x, b1v.y, b1v.z, b1v.w};
#pragma unroll
      for (int i = 0; i < 8; ++i)
#pragma unroll
        for (int j = 0; j < 8; ++j) acc[i][j] += av[i] * bv[j];
    }
  }

  const int ncol0 = bn * 128 + tx * 8;
  float bias[8];
#pragma unroll
  for (int j = 0; j < 8; ++j) {
    float bb = b1[ncol0 + j];
    if (b2) bb += b2[ncol0 + j];
    bias[j] = bb;
  }
#pragma unroll
  for (int i = 0; i < 8; ++i) {
    size_t row = (size_t)bm * 128 + ty * 8 + i;
    float* yp = Y + row * (size_t)ldy + ncol0;
    float out[8];
#pragma unroll
    for (int j = 0; j < 8; ++j) {
      float v = acc[i][j] + bias[j];
      if (ACT) v = tanhf(v);
      out[j] = v;
    }
    *(float4*)(yp)     = make_float4(out[0], out[1], out[2], out[3]);
    *(float4*)(yp + 4) = make_float4(out[4], out[5], out[6], out[7]);
  }
}

// ---------------------------------------------------------------------------
// Attention fusion (unchanged).
// ---------------------------------------------------------------------------
__global__ __launch_bounds__(256) void fusion_kernel(
    const float* __restrict__ F, const float* __restrict__ CTX,
    float* __restrict__ FU)
{
  const int row = blockIdx.x * 4 + (threadIdx.x >> 6);
  const int lane = threadIdx.x & 63;
  const float* a = F + (size_t)row * 1536;
  const float* v = a + 512;
  const float* l = a + 1024;
  const float* c = CTX + (size_t)row * 512;
  float sa = 0.f, sv = 0.f, sl = 0.f;
  for (int k = lane; k < 512; k += 64) {
    float cv = c[k];
    sa += a[k] * cv; sv += v[k] * cv; sl += l[k] * cv;
  }
#pragma unroll
  for (int off = 1; off < 64; off <<= 1) {
    sa += __shfl_xor(sa, off);
    sv += __shfl_xor(sv, off);
    sl += __shfl_xor(sl, off);
  }
  float m = fmaxf(sa, fmaxf(sv, sl));
  float ea = expf(sa - m), ev = expf(sv - m), el = expf(sl - m);
  float inv = 1.0f / (ea + ev + el);
  float wa = ea * inv, wv = ev * inv, wl = el * inv;
  float* fu = FU + (size_t)row * 512;
  for (int k = lane; k < 512; k += 64)
    fu[k] = wa * a[k] + wv * v[k] + wl * l[k];
}

// ---------------------------------------------------------------------------
// MFMA persistent LSTM, all 16 batches fused per MFMA.
//   gates[2048,16] = Whh[2048,512] @ h[512,16]  via mfma_f32_16x16x32_bf16.
// 32 WGs; WG wg owns units u0=wg*16..+15 for ALL batches; wave w = gate w
// (rows w*512+u0..+15). Weights split-precision bf16 (hi+lo) A-frags in
// VGPRs: 2 MFMA per K-tile, weight error ~2^-18. h communicated bf16 via
// tagged u64 ring words: (tag<<32)|(h[b+8]<<16)|h[b], word idx b*512+unit.
// C-initializer of the MFMA = G frag (4 scalar dwords, full-sector reads).
// D layout: row=(lane>>4)*4+reg (unit), col=lane&15 (batch) [m89-verified].
// A: A[m=lane&15][k=(lane>>4)*8+j]; B: B[k=(lane>>4)*8+j][n=lane&15].
// LDS h staged bf16 [16][520] (row pad 8 bf16 -> conflict-free b128 B-reads).
// Ring depth 4 (skew between WGs <=1 step since every WG needs all of h;
// publish t+1 hits slot (t+1)&3 while oldest pending read is (t-1)&3 — safe).
// 0xAA poison => tag 0xAAAAAAAA, never matches want in [0,2047).
// ---------------------------------------------------------------------------
__global__ __launch_bounds__(256, 1) void lstm_kernel(
    const float* __restrict__ G,    // [B,S,2048] = x@Wih.T + bih + bhh
    const float* __restrict__ Whh,  // [2048,512]
    const float* __restrict__ h0,   // [B,512]
    const float* __restrict__ c0,   // [B,512]
    unsigned long long* __restrict__ ring,  // [4][4096]
    float* __restrict__ r_out,      // [B,S,512]
    float* __restrict__ hT,         // [B,512]
    float* __restrict__ cT)         // [B,512]
{
  const int wg = blockIdx.x;        // 0..31
  const int u0 = wg << 4;           // unit base
  const int tid = threadIdx.x;
  const int w = tid >> 6;           // wave index = gate (i,f,g,o)
  const int lane = tid & 63;
  const int mn = lane & 15;         // m (A) / n (B) / col (D)
  const int kq = lane >> 4;         // quad

  __shared__ unsigned int h_u32[16 * 260];  // bf16 h, [batch][520] (pad 8)
  __shared__ float g_lds[4][16][17];        // [gate][unit][batch] (pad)

  // ---- one-time: Whh slice as split-precision bf16 A-frags (128 VGPRs) ----
  short8 wh[16], wl[16];
  {
    const float* wrow = Whh + (size_t)(w * 512 + u0 + mn) * 512;
#pragma unroll
    for (int kt = 0; kt < 16; ++kt) {
      const float* p = wrow + kt * 32 + kq * 8;
      float4 x0 = *(const float4*)p;
      float4 x1 = *(const float4*)(p + 4);
      float xs[8] = {x0.x, x0.y, x0.z, x0.w, x1.x, x1.y, x1.z, x1.w};
      short8 hi, lo;
#pragma unroll
      for (int j = 0; j < 8; ++j) {
        unsigned short hb = f2bf(xs[j]);
        float hf = __builtin_bit_cast(float, (unsigned)hb << 16);
        hi[j] = (short)hb;
        lo[j] = (short)f2bf(xs[j] - hf);
      }
      wh[kt] = hi;
      wl[kt] = lo;
    }
  }

  // pointwise mapping: thread <-> (unit pu, batch pb)
  const int pu = tid >> 4, pb = tid & 15;
  float c_reg = c0[pb * H_ + u0 + pu];

  // poll mapping: thread polls 16 ring words (batch-pair b7, units Ub..Ub+15)
  const int b7 = tid >> 5;               // 0..7
  const int Ub = (tid & 31) * 16;        // 0..496

  for (int t = 0; t < S_; ++t) {
    // C-init from G: acc0[r] = G[b=mn][t][w*512 + u0 + kq*4 + r]
    floatx4 acc0, acc1 = {0,0,0,0}, acc2 = {0,0,0,0}, acc3 = {0,0,0,0};
    {
      const size_t gb = ((size_t)mn * S_ + t) * 2048 + (size_t)(w * 512 + u0 + kq * 4);
#pragma unroll
      for (int r = 0; r < 4; ++r) acc0[r] = G[gb + r];
    }

    if (t == 0) {
      // stage h0 -> bf16 LDS
      const int sb = tid >> 4, sk = (tid & 15) * 32;
      const float* hp = h0 + sb * H_ + sk;
      unsigned int* dst = &h_u32[sb * 260 + sk / 2];
#pragma unroll
      for (int i = 0; i < 8; ++i) {
        float4 x = *(const float4*)(hp + i * 4);
        dst[i * 2]     = (unsigned)f2bf(x.x) | ((unsigned)f2bf(x.y) << 16);
        dst[i * 2 + 1] = (unsigned)f2bf(x.z) | ((unsigned)f2bf(x.w) << 16);
      }
    } else {
      const unsigned want = (unsigned)(t - 1);
      const unsigned long long* slot = ring + (size_t)((t - 1) & 3) * 4096;
      unsigned long long v[16];
      bool ok;
      do {
        ok = true;
#pragma unroll
        for (int i = 0; i < 16; ++i)
          v[i] = __hip_atomic_load(slot + b7 * 512 + Ub + i,
                                   __ATOMIC_RELAXED, __HIP_MEMORY_SCOPE_AGENT);
#pragma unroll
        for (int i = 0; i < 16; ++i)
          ok = ok && ((unsigned)(v[i] >> 32) == want);
      } while (!ok);
      // strip tags: lows -> batch b7, highs -> batch b7+8
      unsigned int* d0 = &h_u32[b7 * 260 + Ub / 2];
      unsigned int* d1 = &h_u32[(b7 + 8) * 260 + Ub / 2];
#pragma unroll
      for (int i = 0; i < 8; ++i) {
        d0[i] = (unsigned)(v[2 * i] & 0xffffu) |
                ((unsigned)(v[2 * i + 1] & 0xffffu) << 16);
        d1[i] = ((unsigned)(v[2 * i] >> 16) & 0xffffu) |
                (((unsigned)(v[2 * i + 1] >> 16) & 0xffffu) << 16);
      }
    }
    __syncthreads();

    // 16 K-tiles x 2 MFMA (hi/lo), 4 interleaved acc chains
#pragma unroll
    for (int kt = 0; kt < 16; ++kt) {
      short8 bf = *(const short8*)&h_u32[mn * 260 + kt * 16 + kq * 4];
      if (kt & 1) {
        acc2 = __builtin_amdgcn_mfma_f32_16x16x32_bf16(wh[kt], bf, acc2, 0, 0, 0);
        acc3 = __builtin_amdgcn_mfma_f32_16x16x32_bf16(wl[kt], bf, acc3, 0, 0, 0);
      } else {
        acc0 = __builtin_amdgcn_mfma_f32_16x16x32_bf16(wh[kt], bf, acc0, 0, 0, 0);
        acc1 = __builtin_amdgcn_mfma_f32_16x16x32_bf16(wl[kt], bf, acc1, 0, 0, 0);
      }
    }
#pragma unroll
    for (int r = 0; r < 4; ++r)
      g_lds[w][kq * 4 + r][mn] = (acc0[r] + acc1[r]) + (acc2[r] + acc3[r]);
    __syncthreads();

    // pointwise for (u0+pu, pb)
    float iv = g_lds[0][pu][pb], fv = g_lds[1][pu][pb];
    float gv = g_lds[2][pu][pb], ov = g_lds[3][pu][pb];
    float ig = 1.f / (1.f + expf(-iv));
    float fg = 1.f / (1.f + expf(-fv));
    float gg = tanhf(gv);
    float og = 1.f / (1.f + expf(-ov));
    c_reg = fg * c_reg + ig * gg;
    float hn = og * tanhf(c_reg);
    r_out[((size_t)pb * S_ + t) * H_ + u0 + pu] = hn;

    unsigned hb16 = (unsigned)f2bf(hn);
    unsigned other = (unsigned)__shfl_xor((int)hb16, 8);  // partner batch pb^8
    if ((pb & 8) == 0) {
      unsigned long long word =
          ((unsigned long long)(unsigned)t << 32) |
          ((unsigned long long)(other & 0xffffu) << 16) |
          (unsigned long long)(hb16 & 0xffffu);
      __hip_atomic_store(ring + (size_t)(t & 3) * 4096 + pb * 512 + (u0 + pu),
                         word, __ATOMIC_RELAXED, __HIP_MEMORY_SCOPE_AGENT);
    }
    if (t == S_ - 1) {
      hT[pb * H_ + u0 + pu] = hn;
      cT[pb * H_ + u0 + pu] = c_reg;
    }
    // no barrier needed here: next iteration's h_u32/g_lds writes are
    // separated from this step's reads by the next __syncthreads pair.
  }
}

// ---------------------------------------------------------------------------
// ws layout (bytes):
//   [0, 201326592)            : F [32768,1536] fp32 (a|v|l)
//   [201326592, 268435456)    : CTX [32768,512]
//   [268435456, 335544320)    : FU  [32768,512]
//   [0, 268435456)            : G [B,S,2048] (overwrites dead F+CTX; FU safe)
//   [335544320, +131072)      : tagged h ring [4][4096] u64
// Total ≈ 336 MB (< R1's proven 403 MB footprint).
// ---------------------------------------------------------------------------
extern "C" void kernel_launch(void* const* d_in, const int* in_sizes, int n_in,
                              void* d_out, int out_size, void* d_ws, size_t ws_size,
                              hipStream_t stream)
{
  const float* a_in = (const float*)d_in[0];
  const float* v_in = (const float*)d_in[1];
  const float* l_in = (const float*)d_in[2];
  const float* h0   = (const float*)d_in[3];
  const float* c0   = (const float*)d_in[4];
  const float* Wa = (const float*)d_in[5];   const float* ba = (const float*)d_in[6];
  const float* Wv = (const float*)d_in[7];   const float* bv = (const float*)d_in[8];
  const float* Wl = (const float*)d_in[9];   const float* bl = (const float*)d_in[10];
  const float* Wc = (const float*)d_in[11];  const float* bc = (const float*)d_in[12];
  const float* Wih = (const float*)d_in[13]; const float* Whh = (const float*)d_in[14];
  const float* bih = (const float*)d_in[15]; const float* bhh = (const float*)d_in[16];

  char* ws = (char*)d_ws;
  float* Fbuf = (float*)ws;
  float* Gbuf = (float*)ws;
  float* CTX  = (float*)(ws + 201326592ull);
  float* FU   = (float*)(ws + 268435456ull);
  unsigned long long* ringp = (unsigned long long*)(ws + 335544320ull);

  dim3 blk(256);
  gemm_xwt<0><<<dim3(256, 4), blk, 0, stream>>>(a_in, Wa, ba, nullptr, Fbuf + 0,    512,  1536);
  gemm_xwt<0><<<dim3(256, 4), blk, 0, stream>>>(v_in, Wv, bv, nullptr, Fbuf + 512,  768,  1536);
  gemm_xwt<0><<<dim3(256, 4), blk, 0, stream>>>(l_in, Wl, bl, nullptr, Fbuf + 1024, 1024, 1536);
  gemm_xwt<1><<<dim3(256, 4), blk, 0, stream>>>(Fbuf, Wc, bc, nullptr, CTX, 1536, 512);
  fusion_kernel<<<dim3(8192), blk, 0, stream>>>(Fbuf, CTX, FU);
  gemm_xwt<0><<<dim3(256, 16), blk, 0, stream>>>(FU, Wih, bih, bhh, Gbuf, 512, 2048);

  float* out = (float*)d_out;
  lstm_kernel<<<dim3(32), blk, 0, stream>>>(Gbuf, Whh, h0, c0, ringp,
                                            out, out + 16777216ull,
                                            out + 16777216ull + 8192ull);
}